// Round 3
// baseline (1091.077 us; speedup 1.0000x reference)
//
#include <hip/hip_runtime.h>
#include <hip/hip_bf16.h>

// Problem constants (fixed shapes from setup_inputs)
constexpr int NB   = 4;      // batch
constexpr int SL   = 4096;   // sequence length
constexpr int DIMC = 1024;   // model dim
constexpr int NH   = 16;     // heads
constexpr int DHC  = 64;     // head dim
constexpr int NFC  = 64;     // random features
constexpr int NCHK = 32;     // L-chunks for kv partial accumulation
constexpr int LCK  = SL / NCHK;  // 128
constexpr int NCHQ = 32;     // L-chunks for query_ctx
constexpr int LCQ  = SL / NCHQ;  // 128
constexpr float FEPS = 1e-6f;

typedef __attribute__((ext_vector_type(8))) short bf16x8_t;  // 8 bf16 (4 VGPRs)
typedef __attribute__((ext_vector_type(4))) float f32x4_t;   // MFMA accumulator
typedef __attribute__((ext_vector_type(4))) short s16x4_t;

__device__ __forceinline__ float rlane(float v, int i) {
  return __uint_as_float(__builtin_amdgcn_readlane(__float_as_uint(v), i));
}

// ---------------------------------------------------------------------------
// fp32 -> bf16 cast (n divisible by 1024). 4 elements/thread.
// ---------------------------------------------------------------------------
__global__ __launch_bounds__(256) void cast_f32_to_bf16(
    const float* __restrict__ in, short* __restrict__ out, int n)
{
  const int i = (blockIdx.x * 256 + threadIdx.x) * 4;
  if (i >= n) return;
  const f32x4_t v = *(const f32x4_t*)(in + i);
  s16x4_t o;
#pragma unroll
  for (int j = 0; j < 4; j++) {
    __hip_bfloat16 h = __float2bfloat16(v[j]);
    o[j] = *(short*)&h;
  }
  *(s16x4_t*)(out + i) = o;
}

// ---------------------------------------------------------------------------
// Fold W0 into a projection weight:  W2[h*64+f][d] = sum_dh W[h*64+dh][d] * W0[h][dh][f]
// fp32 inputs, bf16 output. grid (16 h, 64 f), block 256 over d.
// ---------------------------------------------------------------------------
__global__ __launch_bounds__(256) void fold_w_kernel(
    const float* __restrict__ W, const float* __restrict__ Wrf, short* __restrict__ W2)
{
  const int h = blockIdx.x, f = blockIdx.y;
  __shared__ float w0[64];
  if (threadIdx.x < 64) w0[threadIdx.x] = Wrf[(h * DHC + threadIdx.x) * NFC + f];
  __syncthreads();
  for (int d = threadIdx.x; d < DIMC; d += 256) {
    float acc = 0.f;
#pragma unroll
    for (int dh = 0; dh < 64; dh++)
      acc = fmaf(W[(size_t)(h * DHC + dh) * DIMC + d], w0[dh], acc);
    __hip_bfloat16 hv = __float2bfloat16(acc);
    W2[(size_t)(h * NFC + f) * DIMC + d] = *(short*)&hv;
  }
}

// b2[h*64+f] = sum_dh b[h*64+dh] * W0[h][dh][f].  grid 16, block 64.
__global__ __launch_bounds__(64) void fold_b_kernel(
    const float* __restrict__ b, const float* __restrict__ Wrf, float* __restrict__ b2)
{
  const int h = blockIdx.x, f = threadIdx.x;
  float acc = 0.f;
#pragma unroll
  for (int dh = 0; dh < 64; dh++)
    acc = fmaf(b[h * DHC + dh], Wrf[(h * DHC + dh) * NFC + f], acc);
  b2[h * NFC + f] = acc;
}

// ---------------------------------------------------------------------------
// GEMM: C[M,1024] = A[M,1024] @ W[1024,1024]^T + bias  (bf16 MFMA, fp32 acc)
// MODE 0: write fp32 C.  MODE 1: write bf16 C.
// MODE 2: don't write C; write ksq[row][head] = sum over the head's 64 cols of
//         (C+bias)^2  (each wave's 64 cols are exactly one head).
// wave = 64x64 tile (4x4 mfma frags), block = 4 waves = 128x128 tile
// grid: (M/128, 1024/128)
// ---------------------------------------------------------------------------
template <int MODE>
__global__ __launch_bounds__(256) void gemm_bias_kernel(
    const short* __restrict__ A, const short* __restrict__ W,
    const float* __restrict__ bias, void* __restrict__ Cout)
{
  constexpr int K = 1024, N = 1024;
  const int lane = threadIdx.x & 63;
  const int wid  = threadIdx.x >> 6;
  const int sub  = lane & 15;
  const int quad = lane >> 4;
  const int row0 = blockIdx.x * 128 + (wid >> 1) * 64;
  const int col0 = blockIdx.y * 128 + (wid & 1) * 64;

  f32x4_t acc[4][4] = {};

  for (int k0 = 0; k0 < K; k0 += 32) {
    const int ka = k0 + quad * 8;
    bf16x8_t a[4], b[4];
#pragma unroll
    for (int i = 0; i < 4; i++)
      a[i] = *(const bf16x8_t*)(A + (size_t)(row0 + i * 16 + sub) * K + ka);
#pragma unroll
    for (int j = 0; j < 4; j++)
      b[j] = *(const bf16x8_t*)(W + (size_t)(col0 + j * 16 + sub) * K + ka);
#pragma unroll
    for (int i = 0; i < 4; i++)
#pragma unroll
      for (int j = 0; j < 4; j++)
        acc[i][j] = __builtin_amdgcn_mfma_f32_16x16x32_bf16(a[i], b[j], acc[i][j], 0, 0, 0);
  }

  if constexpr (MODE == 2) {
    // per-head sum of squares; wave covers exactly head = col0/64
    const int head = col0 >> 6;
    float s[4][4];
#pragma unroll
    for (int i = 0; i < 4; i++)
#pragma unroll
      for (int r = 0; r < 4; r++) s[i][r] = 0.f;
#pragma unroll
    for (int j = 0; j < 4; j++) {
      const float bv = bias[col0 + j * 16 + sub];
#pragma unroll
      for (int i = 0; i < 4; i++)
#pragma unroll
        for (int r = 0; r < 4; r++) {
          const float val = acc[i][j][r] + bv;
          s[i][r] = fmaf(val, val, s[i][r]);
        }
    }
    // reduce across the 16 sub-lanes of each quad group
#pragma unroll
    for (int o = 1; o < 16; o <<= 1)
#pragma unroll
      for (int i = 0; i < 4; i++)
#pragma unroll
        for (int r = 0; r < 4; r++) s[i][r] += __shfl_xor(s[i][r], o);
    if (sub == 0) {
      float* ksq = (float*)Cout;
#pragma unroll
      for (int i = 0; i < 4; i++)
#pragma unroll
        for (int r = 0; r < 4; r++)
          ksq[(size_t)(row0 + i * 16 + quad * 4 + r) * NH + head] = s[i][r];
    }
  } else {
#pragma unroll
    for (int j = 0; j < 4; j++) {
      const int col = col0 + j * 16 + sub;
      const float bv = bias[col];
#pragma unroll
      for (int i = 0; i < 4; i++) {
        const int row = row0 + i * 16 + quad * 4;
#pragma unroll
        for (int r = 0; r < 4; r++) {
          const float val = acc[i][j][r] + bv;
          if constexpr (MODE == 0)
            ((float*)Cout)[(size_t)(row + r) * N + col] = val;
          else
            ((__hip_bfloat16*)Cout)[(size_t)(row + r) * N + col] = __float2bfloat16(val);
        }
      }
    }
  }
}

// ---------------------------------------------------------------------------
// Key summary v2: w[l,f] = exp(klog[l,h,f] - 0.5*ksq[l,h]); accumulate
//   partialN[f,d] += w[l,f]*v[l,d], partialD[f] += w[l,f].
// No max shift: logits ~ -32 +- 8, overflow needs > 88 (~13 sigma).
// grid: (NCHK, NH, NB), block 256 (4 waves; wave handles l = wid mod 4)
// ---------------------------------------------------------------------------
__global__ __launch_bounds__(256) void kv_summary_kernel(
    const float* __restrict__ klog, const float* __restrict__ ksq,
    const __hip_bfloat16* __restrict__ vmat,
    float* __restrict__ pN, float* __restrict__ pD)
{
  const int chunk = blockIdx.x, h = blockIdx.y, b = blockIdx.z;
  const int lane = threadIdx.x & 63, wid = threadIdx.x >> 6;

  float Nacc[64];
#pragma unroll
  for (int f = 0; f < 64; f++) Nacc[f] = 0.f;
  float Dacc = 0.f;

  const int l0 = chunk * LCK;
  for (int li = wid; li < LCK; li += 4) {
    const int token = b * SL + l0 + li;
    const size_t base = (size_t)token * DIMC + h * DHC;
    const float kg = klog[base + lane];                    // klog[l][h][f=lane]
    const float vl = __bfloat162float(vmat[base + lane]);  // v[l][d=lane]
    const float w = __expf(kg - 0.5f * ksq[token * NH + h]);  // w[l, f=lane]
    Dacc += w;
#pragma unroll
    for (int f = 0; f < 64; f++) Nacc[f] = fmaf(rlane(w, f), vl, Nacc[f]);
  }

  // block-level reduction of the 4 waves' Nacc via LDS, then one store
  __shared__ float red[4096];
  for (int t = threadIdx.x; t < 4096; t += 256) red[t] = 0.f;
  __syncthreads();
  for (int r = 0; r < 4; r++) {
    if (wid == r) {
#pragma unroll
      for (int f = 0; f < 64; f++) red[f * 64 + lane] += Nacc[f];
    }
    __syncthreads();
  }
  const size_t pbase = ((size_t)((b * NH + h) * NCHK + chunk)) * 4096;
  for (int t = threadIdx.x; t < 4096; t += 256) pN[pbase + t] = red[t];

  __shared__ float dred[256];
  dred[threadIdx.x] = Dacc;
  __syncthreads();
  if (threadIdx.x < 64) {
    const float dsum = dred[threadIdx.x] + dred[64 + threadIdx.x] +
                       dred[128 + threadIdx.x] + dred[192 + threadIdx.x];
    pD[(size_t)((b * NH + h) * NCHK + chunk) * 64 + threadIdx.x] = dsum;
  }
}

// ---------------------------------------------------------------------------
// Combine chunk partials, normalize by s = sum_f D[f] (softmax denominator).
// grid: (NB*NH, 16 segs), block 256. Every block recomputes sInv (cheap).
// ---------------------------------------------------------------------------
__global__ __launch_bounds__(256) void combine_nd_kernel(
    const float* __restrict__ pN, const float* __restrict__ pD,
    float* __restrict__ Nf, float* __restrict__ Df)
{
  const int bh = blockIdx.x, seg = blockIdx.y;
  __shared__ float sInv;
  float dsum = 0.f;
  if (threadIdx.x < 64) {
    for (int c = 0; c < NCHK; c++)
      dsum += pD[(size_t)(bh * NCHK + c) * 64 + threadIdx.x];
    float s = dsum;
#pragma unroll
    for (int o = 32; o; o >>= 1) s += __shfl_xor(s, o);
    if (threadIdx.x == 0) sInv = 1.f / s;
  }
  __syncthreads();
  const float inv = sInv;
  if (seg == 0 && threadIdx.x < 64) Df[bh * 64 + threadIdx.x] = dsum * inv;
  const int t = seg * 256 + threadIdx.x;
  float acc = 0.f;
  for (int c = 0; c < NCHK; c++)
    acc += pN[((size_t)(bh * NCHK + c)) * 4096 + t];
  Nf[(size_t)bh * 4096 + t] = acc * inv;
}

// ---------------------------------------------------------------------------
// Query feature map + context: phi = softmax_f(qlog[l,h,:]);
//   ctx[d] = (sum_f phi_f N[f,d]) / (sum_f phi_f D[f] + eps)
// grid: (NCHQ, NH, NB), block 256
// ---------------------------------------------------------------------------
__global__ __launch_bounds__(256) void query_ctx_kernel(
    const float* __restrict__ qlog, const float* __restrict__ Nf,
    const float* __restrict__ Df, __hip_bfloat16* __restrict__ ctx)
{
  const int chunk = blockIdx.x, h = blockIdx.y, b = blockIdx.z;
  const int lane = threadIdx.x & 63, wid = threadIdx.x >> 6;

  float Ncol[64];
  const size_t nb = (size_t)(b * NH + h) * 4096;
#pragma unroll
  for (int f = 0; f < 64; f++) Ncol[f] = Nf[nb + f * 64 + lane];  // N[f][d=lane]
  const float Dl = Df[(b * NH + h) * 64 + lane];                   // D[f=lane]

  const int l0 = chunk * LCQ;
  for (int li = wid; li < LCQ; li += 4) {
    const size_t base = ((size_t)(b * SL + l0 + li)) * DIMC + h * DHC;
    const float lg = qlog[base + lane];  // qlogit[f=lane]

    float mx = lg;
#pragma unroll
    for (int o = 32; o; o >>= 1) mx = fmaxf(mx, __shfl_xor(mx, o));
    const float e = __expf(lg - mx);
    float se = e, dt = e * Dl;
#pragma unroll
    for (int o = 32; o; o >>= 1) { se += __shfl_xor(se, o); dt += __shfl_xor(dt, o); }

    float n0 = 0.f, n1 = 0.f, n2 = 0.f, n3 = 0.f;  // 4-way ILP on the chain
#pragma unroll
    for (int f = 0; f < 64; f += 4) {
      n0 = fmaf(rlane(e, f + 0), Ncol[f + 0], n0);
      n1 = fmaf(rlane(e, f + 1), Ncol[f + 1], n1);
      n2 = fmaf(rlane(e, f + 2), Ncol[f + 2], n2);
      n3 = fmaf(rlane(e, f + 3), Ncol[f + 3], n3);
    }
    const float num = ((n0 + n1) + (n2 + n3)) / se;
    const float den = dt / se;
    ctx[base + lane] = __float2bfloat16(num / (den + FEPS));
  }
}

// ---------------------------------------------------------------------------
extern "C" void kernel_launch(void* const* d_in, const int* in_sizes, int n_in,
                              void* d_out, int out_size, void* d_ws, size_t ws_size,
                              hipStream_t stream) {
  (void)in_sizes; (void)n_in; (void)out_size; (void)ws_size;
  const float* x   = (const float*)d_in[0];
  const float* Wq  = (const float*)d_in[1];
  const float* bq  = (const float*)d_in[2];
  const float* Wk  = (const float*)d_in[3];
  const float* bk  = (const float*)d_in[4];
  const float* Wv  = (const float*)d_in[5];
  const float* bv  = (const float*)d_in[6];
  const float* Wo  = (const float*)d_in[7];
  const float* bo  = (const float*)d_in[8];
  const float* Wrf = (const float*)d_in[9];
  float* out = (float*)d_out;

  constexpr size_t MiB = 1u << 20;
  constexpr size_t NTOK = (size_t)NB * SL;            // 16384
  constexpr size_t XN   = NTOK * DIMC;
  constexpr size_t WN   = (size_t)DIMC * DIMC;

  char* ws = (char*)d_ws;
  short* xb   = (short*)(ws);                // bf16 x, 32 MiB; reused as ctx
  short* Wkb  = (short*)(ws + 32 * MiB);     // 2 MiB each
  short* Wvb  = (short*)(ws + 34 * MiB);
  short* Wob  = (short*)(ws + 36 * MiB);
  short* Wq2b = (short*)(ws + 38 * MiB);     // folded Wq^T W0 (bf16)
  short* Wk2b = (short*)(ws + 40 * MiB);     // folded Wk^T W0 (bf16)
  float* bq2  = (float*)(ws + 42 * MiB);     // 4 KiB
  float* bk2  = (float*)(ws + 42 * MiB + 8192);
  float* klog = (float*)(ws + 44 * MiB);     // fp32, 64 MiB; reused as qlog
  float* ksq  = (float*)(ws + 108 * MiB);    // fp32 [NTOK][NH], 1 MiB
  __hip_bfloat16* vb = (__hip_bfloat16*)(ws + 109 * MiB);  // bf16 v, 32 MiB
  float* pN   = (float*)(ws + 141 * MiB);    // 32 MiB
  float* pD   = (float*)(ws + 173 * MiB);    // 512 KiB
  float* Nf   = (float*)(ws + 174 * MiB);    // 1 MiB
  float* Df   = (float*)(ws + 175 * MiB);    // 16 KiB
  float* qlog = klog;                        // alias: klog dead after kv_summary
  __hip_bfloat16* ctxb = (__hip_bfloat16*)xb; // alias: xb dead after qlog GEMM

  const dim3 blk(256);

  // casts: fp32 -> bf16 (Wq never needed in bf16 — only its folded version)
  cast_f32_to_bf16<<<dim3(XN / 1024), blk, 0, stream>>>(x, xb, (int)XN);
  cast_f32_to_bf16<<<dim3(WN / 1024), blk, 0, stream>>>(Wk, Wkb, (int)WN);
  cast_f32_to_bf16<<<dim3(WN / 1024), blk, 0, stream>>>(Wv, Wvb, (int)WN);
  cast_f32_to_bf16<<<dim3(WN / 1024), blk, 0, stream>>>(Wo, Wob, (int)WN);

  // fold W0 into q/k projections (fp32 math, bf16 result)
  fold_w_kernel<<<dim3(NH, NFC), blk, 0, stream>>>(Wq, Wrf, Wq2b);
  fold_w_kernel<<<dim3(NH, NFC), blk, 0, stream>>>(Wk, Wrf, Wk2b);
  fold_b_kernel<<<dim3(NH), dim3(64), 0, stream>>>(bq, Wrf, bq2);
  fold_b_kernel<<<dim3(NH), dim3(64), 0, stream>>>(bk, Wrf, bk2);

  const dim3 gg(NTOK / 128, DIMC / 128);
  gemm_bias_kernel<0><<<gg, blk, 0, stream>>>(xb, Wk2b, bk2, klog);
  gemm_bias_kernel<2><<<gg, blk, 0, stream>>>(xb, Wkb, bk, ksq);
  gemm_bias_kernel<1><<<gg, blk, 0, stream>>>(xb, Wvb, bv, vb);

  kv_summary_kernel<<<dim3(NCHK, NH, NB), blk, 0, stream>>>(klog, ksq, vb, pN, pD);
  combine_nd_kernel<<<dim3(NB * NH, 16), blk, 0, stream>>>(pN, pD, Nf, Df);

  gemm_bias_kernel<0><<<gg, blk, 0, stream>>>(xb, Wq2b, bq2, qlog);
  query_ctx_kernel<<<dim3(NCHQ, NH, NB), blk, 0, stream>>>(qlog, Nf, Df, ctxb);

  gemm_bias_kernel<0><<<gg, blk, 0, stream>>>((const short*)ctxb, Wob, bo, out);
}

// Round 4
// 656.072 us; speedup vs baseline: 1.6630x; 1.6630x over previous
//
#include <hip/hip_runtime.h>
#include <hip/hip_bf16.h>

// Problem constants (fixed shapes from setup_inputs)
constexpr int NB   = 4;      // batch
constexpr int SL   = 4096;   // sequence length
constexpr int DIMC = 1024;   // model dim
constexpr int NH   = 16;     // heads
constexpr int DHC  = 64;     // head dim
constexpr int NFC  = 64;     // random features
constexpr int NCHK = 32;     // L-chunks for kv partial accumulation
constexpr int LCK  = SL / NCHK;  // 128
constexpr int NCHQ = 32;     // L-chunks for query_ctx
constexpr int LCQ  = SL / NCHQ;  // 128
constexpr float FEPS = 1e-6f;

typedef __attribute__((ext_vector_type(8))) short bf16x8_t;  // 8 bf16 (4 VGPRs)
typedef __attribute__((ext_vector_type(4))) float f32x4_t;   // MFMA accumulator
typedef __attribute__((ext_vector_type(4))) short s16x4_t;

__device__ __forceinline__ float rlane(float v, int i) {
  return __uint_as_float(__builtin_amdgcn_readlane(__float_as_uint(v), i));
}

// async global->LDS, 16 B per lane; LDS dest = wave-uniform base + lane*16
__device__ __forceinline__ void load_lds_16B(const short* g, short* l) {
  __builtin_amdgcn_global_load_lds(
      (__attribute__((address_space(1))) void*)(g),
      (__attribute__((address_space(3))) void*)(l), 16, 0, 0);
}

// ---------------------------------------------------------------------------
// fp32 -> bf16 cast (n divisible by 1024). 4 elements/thread.
// ---------------------------------------------------------------------------
__global__ __launch_bounds__(256) void cast_f32_to_bf16(
    const float* __restrict__ in, short* __restrict__ out, int n)
{
  const int i = (blockIdx.x * 256 + threadIdx.x) * 4;
  if (i >= n) return;
  const f32x4_t v = *(const f32x4_t*)(in + i);
  s16x4_t o;
#pragma unroll
  for (int j = 0; j < 4; j++) {
    __hip_bfloat16 h = __float2bfloat16(v[j]);
    o[j] = *(short*)&h;
  }
  *(s16x4_t*)(out + i) = o;
}

// ---------------------------------------------------------------------------
// Fold W0 into q projection:  W2[h*64+f][d] = sum_dh W[h*64+dh][d] * W0[h][dh][f]
// ---------------------------------------------------------------------------
__global__ __launch_bounds__(256) void fold_w_kernel(
    const float* __restrict__ W, const float* __restrict__ Wrf, short* __restrict__ W2)
{
  const int h = blockIdx.x, f = blockIdx.y;
  __shared__ float w0[64];
  if (threadIdx.x < 64) w0[threadIdx.x] = Wrf[(h * DHC + threadIdx.x) * NFC + f];
  __syncthreads();
  for (int d = threadIdx.x; d < DIMC; d += 256) {
    float acc = 0.f;
#pragma unroll
    for (int dh = 0; dh < 64; dh++)
      acc = fmaf(W[(size_t)(h * DHC + dh) * DIMC + d], w0[dh], acc);
    __hip_bfloat16 hv = __float2bfloat16(acc);
    W2[(size_t)(h * NFC + f) * DIMC + d] = *(short*)&hv;
  }
}

__global__ __launch_bounds__(64) void fold_b_kernel(
    const float* __restrict__ b, const float* __restrict__ Wrf, float* __restrict__ b2)
{
  const int h = blockIdx.x, f = threadIdx.x;
  float acc = 0.f;
#pragma unroll
  for (int dh = 0; dh < 64; dh++)
    acc = fmaf(b[h * DHC + dh], Wrf[(h * DHC + dh) * NFC + f], acc);
  b2[h * NFC + f] = acc;
}

// ---------------------------------------------------------------------------
// W0 transposed per head, split bf16 hi/lo: W0T[h][f][dh]
// ---------------------------------------------------------------------------
__global__ __launch_bounds__(256) void prep_w0t_kernel(
    const float* __restrict__ Wrf, short* __restrict__ Whi, short* __restrict__ Wlo)
{
  const int h = blockIdx.x;
  for (int t = threadIdx.x; t < 4096; t += 256) {
    const int f = t >> 6, dh = t & 63;
    const float w = Wrf[(size_t)h * 4096 + dh * 64 + f];
    __hip_bfloat16 hi = __float2bfloat16(w);
    const float rem = w - __bfloat162float(hi);
    __hip_bfloat16 lo = __float2bfloat16(rem);
    Whi[(size_t)h * 4096 + t] = *(short*)&hi;
    Wlo[(size_t)h * 4096 + t] = *(short*)&lo;
  }
}

// ---------------------------------------------------------------------------
// LDS-staged GEMM (m97 structure): C[M,1024] = A[M,1024] @ W[1024,1024]^T + bias
// 128x128 block tile, BK=64, global_load_lds width=16, XOR-16B-chunk swizzle.
// MODE 0: fp32 C.  MODE 1: bf16 C.
// MODE 3: C as bf16 hi (C0) + bf16 lo (C1), plus ksq[row][head] = sum_d (val^2)
// grid: (M/128, 8), block 256 (4 waves; wave = 64x64 quadrant)
// ---------------------------------------------------------------------------
template <int MODE>
__global__ __launch_bounds__(256) void gemm_lds_kernel(
    const short* __restrict__ A, const short* __restrict__ W,
    const float* __restrict__ bias, void* __restrict__ C0,
    void* __restrict__ C1, float* __restrict__ Ks)
{
  constexpr int K = 1024, N = 1024;
  const int lane = threadIdx.x & 63;
  const int wid  = threadIdx.x >> 6;
  const int sub  = lane & 15;
  const int quad = lane >> 4;
  const int wr   = (wid >> 1) * 64;   // wave row base in tile
  const int wc   = (wid & 1) * 64;    // wave col base in tile
  const int row0 = blockIdx.x * 128;
  const int col0 = blockIdx.y * 128;

  __shared__ short As[128 * 64];  // 16 KiB, row = 128 B (8 x 16B chunks)
  __shared__ short Bs[128 * 64];

  f32x4_t acc[4][4] = {};

  // staging lane mapping: row_local = lane>>3, chunk slot = lane&7;
  // LDS[r][slot] holds global chunk (slot ^ (r&7))  -> conflict-free ds_read
  const int srow = lane >> 3;
  for (int k0 = 0; k0 < K; k0 += 64) {
#pragma unroll
    for (int t = 0; t < 4; t++) {
      const int R   = wid * 32 + t * 8;
      const int row = R + srow;
      const int c   = (lane & 7) ^ (row & 7);
      load_lds_16B(A + (size_t)(row0 + row) * K + k0 + c * 8, As + R * 64);
      load_lds_16B(W + (size_t)(col0 + row) * K + k0 + c * 8, Bs + R * 64);
    }
    __syncthreads();

    bf16x8_t a[2][4], b[2][4];
#pragma unroll
    for (int ks = 0; ks < 2; ks++) {
#pragma unroll
      for (int i = 0; i < 4; i++) {
        const int ra = wr + i * 16 + sub;
        a[ks][i] = *(const bf16x8_t*)(As + ra * 64 + (((ks * 4 + quad) ^ (ra & 7)) * 8));
        const int rb = wc + i * 16 + sub;
        b[ks][i] = *(const bf16x8_t*)(Bs + rb * 64 + (((ks * 4 + quad) ^ (rb & 7)) * 8));
      }
    }
#pragma unroll
    for (int ks = 0; ks < 2; ks++)
#pragma unroll
      for (int i = 0; i < 4; i++)
#pragma unroll
        for (int j = 0; j < 4; j++)
          acc[i][j] = __builtin_amdgcn_mfma_f32_16x16x32_bf16(a[ks][i], b[ks][j], acc[i][j], 0, 0, 0);
    __syncthreads();
  }

  const int rb0 = row0 + wr;
  const int cb0 = col0 + wc;
  if constexpr (MODE == 3) {
    const int head = cb0 >> 6;  // wave's 64 cols = exactly one head
    __hip_bfloat16* khi = (__hip_bfloat16*)C0;
    __hip_bfloat16* klo = (__hip_bfloat16*)C1;
    float s[4][4];
#pragma unroll
    for (int i = 0; i < 4; i++)
#pragma unroll
      for (int r = 0; r < 4; r++) s[i][r] = 0.f;
#pragma unroll
    for (int j = 0; j < 4; j++) {
      const int col = cb0 + j * 16 + sub;
      const float bv = bias[col];
#pragma unroll
      for (int i = 0; i < 4; i++) {
        const int row = rb0 + i * 16 + quad * 4;
#pragma unroll
        for (int r = 0; r < 4; r++) {
          const float val = acc[i][j][r] + bv;
          const __hip_bfloat16 hi = __float2bfloat16(val);
          const float rem = val - __bfloat162float(hi);
          khi[(size_t)(row + r) * N + col] = hi;
          klo[(size_t)(row + r) * N + col] = __float2bfloat16(rem);
          s[i][r] = fmaf(val, val, s[i][r]);
        }
      }
    }
#pragma unroll
    for (int o = 1; o < 16; o <<= 1)
#pragma unroll
      for (int i = 0; i < 4; i++)
#pragma unroll
        for (int r = 0; r < 4; r++) s[i][r] += __shfl_xor(s[i][r], o);
    if (sub == 0) {
#pragma unroll
      for (int i = 0; i < 4; i++)
#pragma unroll
        for (int r = 0; r < 4; r++)
          Ks[(size_t)(rb0 + i * 16 + quad * 4 + r) * NH + head] = s[i][r];
    }
  } else {
#pragma unroll
    for (int j = 0; j < 4; j++) {
      const int col = cb0 + j * 16 + sub;
      const float bv = bias[col];
#pragma unroll
      for (int i = 0; i < 4; i++) {
        const int row = rb0 + i * 16 + quad * 4;
#pragma unroll
        for (int r = 0; r < 4; r++) {
          const float val = acc[i][j][r] + bv;
          if constexpr (MODE == 0)
            ((float*)C0)[(size_t)(row + r) * N + col] = val;
          else
            ((__hip_bfloat16*)C0)[(size_t)(row + r) * N + col] = __float2bfloat16(val);
        }
      }
    }
  }
}

// ---------------------------------------------------------------------------
// klog[tok][h*64+f] = sum_dh k[tok][h*64+dh] * W0[h][dh][f]
// k given as bf16 hi+lo split; 3-term hi/lo MFMA products for ~fp32 precision.
// grid: (128 token-blocks, 16 heads), block 256; wave handles 32 tokens.
// ---------------------------------------------------------------------------
__global__ __launch_bounds__(256) void klog_gemm_kernel(
    const short* __restrict__ khi, const short* __restrict__ klo,
    const short* __restrict__ Whi, const short* __restrict__ Wlo,
    float* __restrict__ klog)
{
  const int lane = threadIdx.x & 63, wid = threadIdx.x >> 6;
  const int sub = lane & 15, quad = lane >> 4;
  const int h = blockIdx.y;
  const int tok0 = blockIdx.x * 128 + wid * 32;
  const short* Bh = Whi + (size_t)h * 4096;
  const short* Bl = Wlo + (size_t)h * 4096;

  f32x4_t acc[2][4] = {};
#pragma unroll
  for (int ks = 0; ks < 2; ks++) {
    const int ko = ks * 32 + quad * 8;
    bf16x8_t ah[2], al[2], bh[4], bl[4];
#pragma unroll
    for (int i = 0; i < 2; i++) {
      const size_t base = (size_t)(tok0 + i * 16 + sub) * DIMC + h * 64 + ko;
      ah[i] = *(const bf16x8_t*)(khi + base);
      al[i] = *(const bf16x8_t*)(klo + base);
    }
#pragma unroll
    for (int j = 0; j < 4; j++) {
      const size_t base = (size_t)(j * 16 + sub) * 64 + ko;
      bh[j] = *(const bf16x8_t*)(Bh + base);
      bl[j] = *(const bf16x8_t*)(Bl + base);
    }
#pragma unroll
    for (int i = 0; i < 2; i++)
#pragma unroll
      for (int j = 0; j < 4; j++) {
        acc[i][j] = __builtin_amdgcn_mfma_f32_16x16x32_bf16(ah[i], bh[j], acc[i][j], 0, 0, 0);
        acc[i][j] = __builtin_amdgcn_mfma_f32_16x16x32_bf16(al[i], bh[j], acc[i][j], 0, 0, 0);
        acc[i][j] = __builtin_amdgcn_mfma_f32_16x16x32_bf16(ah[i], bl[j], acc[i][j], 0, 0, 0);
      }
  }
#pragma unroll
  for (int i = 0; i < 2; i++)
#pragma unroll
    for (int j = 0; j < 4; j++)
#pragma unroll
      for (int r = 0; r < 4; r++)
        klog[(size_t)(tok0 + i * 16 + quad * 4 + r) * DIMC + h * 64 + j * 16 + sub] = acc[i][j][r];
}

// ---------------------------------------------------------------------------
// Key summary: w[l,f] = exp(klog[l,h,f] - 0.5*ksq[l,h]); accumulate
//   partialN[f,d] += w[l,f]*v[l,d], partialD[f] += w[l,f].
// grid: (NCHK, NH, NB), block 256
// ---------------------------------------------------------------------------
__global__ __launch_bounds__(256) void kv_summary_kernel(
    const float* __restrict__ klog, const float* __restrict__ ksq,
    const __hip_bfloat16* __restrict__ vmat,
    float* __restrict__ pN, float* __restrict__ pD)
{
  const int chunk = blockIdx.x, h = blockIdx.y, b = blockIdx.z;
  const int lane = threadIdx.x & 63, wid = threadIdx.x >> 6;

  float Nacc[64];
#pragma unroll
  for (int f = 0; f < 64; f++) Nacc[f] = 0.f;
  float Dacc = 0.f;

  const int l0 = chunk * LCK;
  for (int li = wid; li < LCK; li += 4) {
    const int token = b * SL + l0 + li;
    const size_t base = (size_t)token * DIMC + h * DHC;
    const float kg = klog[base + lane];
    const float vl = __bfloat162float(vmat[base + lane]);
    const float w = __expf(kg - 0.5f * ksq[token * NH + h]);
    Dacc += w;
#pragma unroll
    for (int f = 0; f < 64; f++) Nacc[f] = fmaf(rlane(w, f), vl, Nacc[f]);
  }

  __shared__ float red[4096];
  for (int t = threadIdx.x; t < 4096; t += 256) red[t] = 0.f;
  __syncthreads();
  for (int r = 0; r < 4; r++) {
    if (wid == r) {
#pragma unroll
      for (int f = 0; f < 64; f++) red[f * 64 + lane] += Nacc[f];
    }
    __syncthreads();
  }
  const size_t pbase = ((size_t)((b * NH + h) * NCHK + chunk)) * 4096;
  for (int t = threadIdx.x; t < 4096; t += 256) pN[pbase + t] = red[t];

  __shared__ float dred[256];
  dred[threadIdx.x] = Dacc;
  __syncthreads();
  if (threadIdx.x < 64) {
    const float dsum = dred[threadIdx.x] + dred[64 + threadIdx.x] +
                       dred[128 + threadIdx.x] + dred[192 + threadIdx.x];
    pD[(size_t)((b * NH + h) * NCHK + chunk) * 64 + threadIdx.x] = dsum;
  }
}

// ---------------------------------------------------------------------------
// Combine chunk partials, normalize by s = sum_f D[f].
// grid: (NB*NH, 16), block 256
// ---------------------------------------------------------------------------
__global__ __launch_bounds__(256) void combine_nd_kernel(
    const float* __restrict__ pN, const float* __restrict__ pD,
    float* __restrict__ Nf, float* __restrict__ Df)
{
  const int bh = blockIdx.x, seg = blockIdx.y;
  __shared__ float sInv;
  float dsum = 0.f;
  if (threadIdx.x < 64) {
    for (int c = 0; c < NCHK; c++)
      dsum += pD[(size_t)(bh * NCHK + c) * 64 + threadIdx.x];
    float s = dsum;
#pragma unroll
    for (int o = 32; o; o >>= 1) s += __shfl_xor(s, o);
    if (threadIdx.x == 0) sInv = 1.f / s;
  }
  __syncthreads();
  const float inv = sInv;
  if (seg == 0 && threadIdx.x < 64) Df[bh * 64 + threadIdx.x] = dsum * inv;
  const int t = seg * 256 + threadIdx.x;
  float acc = 0.f;
  for (int c = 0; c < NCHK; c++)
    acc += pN[((size_t)(bh * NCHK + c)) * 4096 + t];
  Nf[(size_t)bh * 4096 + t] = acc * inv;
}

// ---------------------------------------------------------------------------
// Query feature map + context.
// grid: (NCHQ, NH, NB), block 256
// ---------------------------------------------------------------------------
__global__ __launch_bounds__(256) void query_ctx_kernel(
    const float* __restrict__ qlog, const float* __restrict__ Nf,
    const float* __restrict__ Df, __hip_bfloat16* __restrict__ ctx)
{
  const int chunk = blockIdx.x, h = blockIdx.y, b = blockIdx.z;
  const int lane = threadIdx.x & 63, wid = threadIdx.x >> 6;

  float Ncol[64];
  const size_t nb = (size_t)(b * NH + h) * 4096;
#pragma unroll
  for (int f = 0; f < 64; f++) Ncol[f] = Nf[nb + f * 64 + lane];
  const float Dl = Df[(b * NH + h) * 64 + lane];

  const int l0 = chunk * LCQ;
  for (int li = wid; li < LCQ; li += 4) {
    const size_t base = ((size_t)(b * SL + l0 + li)) * DIMC + h * DHC;
    const float lg = qlog[base + lane];

    float mx = lg;
#pragma unroll
    for (int o = 32; o; o >>= 1) mx = fmaxf(mx, __shfl_xor(mx, o));
    const float e = __expf(lg - mx);
    float se = e, dt = e * Dl;
#pragma unroll
    for (int o = 32; o; o >>= 1) { se += __shfl_xor(se, o); dt += __shfl_xor(dt, o); }

    float n0 = 0.f, n1 = 0.f, n2 = 0.f, n3 = 0.f;
#pragma unroll
    for (int f = 0; f < 64; f += 4) {
      n0 = fmaf(rlane(e, f + 0), Ncol[f + 0], n0);
      n1 = fmaf(rlane(e, f + 1), Ncol[f + 1], n1);
      n2 = fmaf(rlane(e, f + 2), Ncol[f + 2], n2);
      n3 = fmaf(rlane(e, f + 3), Ncol[f + 3], n3);
    }
    const float num = ((n0 + n1) + (n2 + n3)) / se;
    const float den = dt / se;
    ctx[base + lane] = __float2bfloat16(num / (den + FEPS));
  }
}

// ---------------------------------------------------------------------------
extern "C" void kernel_launch(void* const* d_in, const int* in_sizes, int n_in,
                              void* d_out, int out_size, void* d_ws, size_t ws_size,
                              hipStream_t stream) {
  (void)in_sizes; (void)n_in; (void)out_size; (void)ws_size;
  const float* x   = (const float*)d_in[0];
  const float* Wq  = (const float*)d_in[1];
  const float* bq  = (const float*)d_in[2];
  const float* Wk  = (const float*)d_in[3];
  const float* bk  = (const float*)d_in[4];
  const float* Wv  = (const float*)d_in[5];
  const float* bv  = (const float*)d_in[6];
  const float* Wo  = (const float*)d_in[7];
  const float* bo  = (const float*)d_in[8];
  const float* Wrf = (const float*)d_in[9];
  float* out = (float*)d_out;

  constexpr size_t MiB = 1u << 20;
  constexpr size_t KiB = 1u << 10;
  constexpr size_t NTOK = (size_t)NB * SL;   // 16384
  constexpr size_t XN   = NTOK * DIMC;
  constexpr size_t WN   = (size_t)DIMC * DIMC;

  char* ws = (char*)d_ws;
  short* xb   = (short*)(ws);                      // bf16 x, 32 MiB; reused as ctx
  short* Wkb  = (short*)(ws + 32 * MiB);
  short* Wvb  = (short*)(ws + 34 * MiB);
  short* Wob  = (short*)(ws + 36 * MiB);
  short* Wq2b = (short*)(ws + 38 * MiB);           // folded Wq^T W0 (bf16)
  float* bq2  = (float*)(ws + 40 * MiB);           // 4 KiB
  short* W0Th = (short*)(ws + 40 * MiB + 64 * KiB);  // 128 KiB
  short* W0Tl = (short*)(ws + 40 * MiB + 192 * KiB); // 128 KiB
  float* klog = (float*)(ws + 44 * MiB);           // fp32, 64 MiB; reused as qlog
  float* ksq  = (float*)(ws + 108 * MiB);          // 1 MiB
  __hip_bfloat16* vb  = (__hip_bfloat16*)(ws + 109 * MiB);  // 32 MiB
  __hip_bfloat16* khi = (__hip_bfloat16*)(ws + 141 * MiB);  // 32 MiB
  __hip_bfloat16* klo = (__hip_bfloat16*)(ws + 173 * MiB);  // 32 MiB
  float* pN   = (float*)(ws + 141 * MiB);          // 32 MiB — overlays khi (dead)
  float* pD   = (float*)(ws + 173 * MiB);          // 512 KiB — overlays klo (dead)
  float* Nf   = (float*)(ws + 174 * MiB);          // 1 MiB
  float* Df   = (float*)(ws + 175 * MiB);          // 16 KiB
  float* qlog = klog;                              // alias: klog dead after kv_summary
  __hip_bfloat16* ctxb = (__hip_bfloat16*)xb;      // alias: xb dead after qlog GEMM

  const dim3 blk(256);

  cast_f32_to_bf16<<<dim3(XN / 1024), blk, 0, stream>>>(x, xb, (int)XN);
  cast_f32_to_bf16<<<dim3(WN / 1024), blk, 0, stream>>>(Wk, Wkb, (int)WN);
  cast_f32_to_bf16<<<dim3(WN / 1024), blk, 0, stream>>>(Wv, Wvb, (int)WN);
  cast_f32_to_bf16<<<dim3(WN / 1024), blk, 0, stream>>>(Wo, Wob, (int)WN);

  fold_w_kernel<<<dim3(NH, NFC), blk, 0, stream>>>(Wq, Wrf, Wq2b);
  fold_b_kernel<<<dim3(NH), dim3(64), 0, stream>>>(bq, Wrf, bq2);
  prep_w0t_kernel<<<dim3(NH), blk, 0, stream>>>(Wrf, W0Th, W0Tl);

  const dim3 gg(NTOK / 128, DIMC / 128);
  gemm_lds_kernel<3><<<gg, blk, 0, stream>>>(xb, Wkb, bk, khi, klo, ksq);
  gemm_lds_kernel<1><<<gg, blk, 0, stream>>>(xb, Wvb, bv, vb, nullptr, nullptr);

  klog_gemm_kernel<<<dim3(NTOK / 128, NH), blk, 0, stream>>>(
      (const short*)khi, (const short*)klo, W0Th, W0Tl, klog);

  kv_summary_kernel<<<dim3(NCHK, NH, NB), blk, 0, stream>>>(klog, ksq, vb, pN, pD);
  combine_nd_kernel<<<dim3(NB * NH, 16), blk, 0, stream>>>(pN, pD, Nf, Df);

  gemm_lds_kernel<0><<<gg, blk, 0, stream>>>(xb, Wq2b, bq2, qlog, nullptr, nullptr);
  query_ctx_kernel<<<dim3(NCHQ, NH, NB), blk, 0, stream>>>(qlog, Nf, Df, ctxb);

  gemm_lds_kernel<0><<<gg, blk, 0, stream>>>((const short*)ctxb, Wob, bo, out, nullptr, nullptr);
}

// Round 5
// 576.411 us; speedup vs baseline: 1.8929x; 1.1382x over previous
//
#include <hip/hip_runtime.h>
#include <hip/hip_bf16.h>

// Problem constants (fixed shapes from setup_inputs)
constexpr int NB   = 4;      // batch
constexpr int SL   = 4096;   // sequence length
constexpr int DIMC = 1024;   // model dim
constexpr int NH   = 16;     // heads
constexpr int DHC  = 64;     // head dim
constexpr int NFC  = 64;     // random features
constexpr int NCHK = 32;     // L-chunks for kv partial accumulation
constexpr int LCK  = SL / NCHK;  // 128
constexpr int NCHQ = 32;     // L-chunks for phi
constexpr int LCQ  = SL / NCHQ;  // 128
constexpr float FEPS = 1e-6f;

typedef __attribute__((ext_vector_type(8))) short bf16x8_t;  // 8 bf16 (4 VGPRs)
typedef __attribute__((ext_vector_type(4))) float f32x4_t;   // MFMA accumulator
typedef __attribute__((ext_vector_type(4))) short s16x4_t;

__device__ __forceinline__ float rlane(float v, int i) {
  return __uint_as_float(__builtin_amdgcn_readlane(__float_as_uint(v), i));
}

// async global->LDS, 16 B per lane; LDS dest = wave-uniform base + lane*16
__device__ __forceinline__ void load_lds_16B(const short* g, short* l) {
  __builtin_amdgcn_global_load_lds(
      (__attribute__((address_space(1))) void*)(g),
      (__attribute__((address_space(3))) void*)(l), 16, 0, 0);
}

// ---------------------------------------------------------------------------
// fp32 -> bf16 cast (n divisible by 1024). 4 elements/thread.
// ---------------------------------------------------------------------------
__global__ __launch_bounds__(256) void cast_f32_to_bf16(
    const float* __restrict__ in, short* __restrict__ out, int n)
{
  const int i = (blockIdx.x * 256 + threadIdx.x) * 4;
  if (i >= n) return;
  const f32x4_t v = *(const f32x4_t*)(in + i);
  s16x4_t o;
#pragma unroll
  for (int j = 0; j < 4; j++) {
    __hip_bfloat16 h = __float2bfloat16(v[j]);
    o[j] = *(short*)&h;
  }
  *(s16x4_t*)(out + i) = o;
}

// ---------------------------------------------------------------------------
// W0 transposed per head, split bf16 hi/lo: W0T[h][f][dh]
// ---------------------------------------------------------------------------
__global__ __launch_bounds__(256) void prep_w0t_kernel(
    const float* __restrict__ Wrf, short* __restrict__ Whi, short* __restrict__ Wlo)
{
  const int h = blockIdx.x;
  for (int t = threadIdx.x; t < 4096; t += 256) {
    const int f = t >> 6, dh = t & 63;
    const float w = Wrf[(size_t)h * 4096 + dh * 64 + f];
    __hip_bfloat16 hi = __float2bfloat16(w);
    const float rem = w - __bfloat162float(hi);
    __hip_bfloat16 lo = __float2bfloat16(rem);
    Whi[(size_t)h * 4096 + t] = *(short*)&hi;
    Wlo[(size_t)h * 4096 + t] = *(short*)&lo;
  }
}

// ---------------------------------------------------------------------------
// LDS-staged GEMM (m97 structure): C[M,1024] = A[M,1024] @ W[1024,1024]^T + bias
// 128x128 block tile, BK=64, global_load_lds width=16, XOR-16B-chunk swizzle.
// MODE 0: fp32 C.  MODE 1: bf16 C.
// MODE 3: C as bf16 hi (C0) + lo (C1) + ksq[row][head] = sum_d val^2
// MODE 4: C as bf16 hi (C0) + lo (C1) only
// grid: (M/128, 8), block 256 (4 waves; wave = 64x64 quadrant)
// ---------------------------------------------------------------------------
template <int MODE>
__global__ __launch_bounds__(256) void gemm_lds_kernel(
    const short* __restrict__ A, const short* __restrict__ W,
    const float* __restrict__ bias, void* __restrict__ C0,
    void* __restrict__ C1, float* __restrict__ Ks)
{
  constexpr int K = 1024, N = 1024;
  const int lane = threadIdx.x & 63;
  const int wid  = threadIdx.x >> 6;
  const int sub  = lane & 15;
  const int quad = lane >> 4;
  const int wr   = (wid >> 1) * 64;
  const int wc   = (wid & 1) * 64;
  const int row0 = blockIdx.x * 128;
  const int col0 = blockIdx.y * 128;

  __shared__ short As[128 * 64];  // 16 KiB, row = 128 B (8 x 16B chunks)
  __shared__ short Bs[128 * 64];

  f32x4_t acc[4][4] = {};

  const int srow = lane >> 3;
  for (int k0 = 0; k0 < K; k0 += 64) {
#pragma unroll
    for (int t = 0; t < 4; t++) {
      const int R   = wid * 32 + t * 8;
      const int row = R + srow;
      const int c   = (lane & 7) ^ (row & 7);
      load_lds_16B(A + (size_t)(row0 + row) * K + k0 + c * 8, As + R * 64);
      load_lds_16B(W + (size_t)(col0 + row) * K + k0 + c * 8, Bs + R * 64);
    }
    __syncthreads();

    bf16x8_t a[2][4], b[2][4];
#pragma unroll
    for (int ks = 0; ks < 2; ks++) {
#pragma unroll
      for (int i = 0; i < 4; i++) {
        const int ra = wr + i * 16 + sub;
        a[ks][i] = *(const bf16x8_t*)(As + ra * 64 + (((ks * 4 + quad) ^ (ra & 7)) * 8));
        const int rb = wc + i * 16 + sub;
        b[ks][i] = *(const bf16x8_t*)(Bs + rb * 64 + (((ks * 4 + quad) ^ (rb & 7)) * 8));
      }
    }
#pragma unroll
    for (int ks = 0; ks < 2; ks++)
#pragma unroll
      for (int i = 0; i < 4; i++)
#pragma unroll
        for (int j = 0; j < 4; j++)
          acc[i][j] = __builtin_amdgcn_mfma_f32_16x16x32_bf16(a[ks][i], b[ks][j], acc[i][j], 0, 0, 0);
    __syncthreads();
  }

  const int rb0 = row0 + wr;
  const int cb0 = col0 + wc;
  if constexpr (MODE == 3 || MODE == 4) {
    __hip_bfloat16* chi = (__hip_bfloat16*)C0;
    __hip_bfloat16* clo = (__hip_bfloat16*)C1;
    float s[4][4];
#pragma unroll
    for (int i = 0; i < 4; i++)
#pragma unroll
      for (int r = 0; r < 4; r++) s[i][r] = 0.f;
#pragma unroll
    for (int j = 0; j < 4; j++) {
      const int col = cb0 + j * 16 + sub;
      const float bv = bias[col];
#pragma unroll
      for (int i = 0; i < 4; i++) {
        const int row = rb0 + i * 16 + quad * 4;
#pragma unroll
        for (int r = 0; r < 4; r++) {
          const float val = acc[i][j][r] + bv;
          const __hip_bfloat16 hi = __float2bfloat16(val);
          const float rem = val - __bfloat162float(hi);
          chi[(size_t)(row + r) * N + col] = hi;
          clo[(size_t)(row + r) * N + col] = __float2bfloat16(rem);
          if constexpr (MODE == 3) s[i][r] = fmaf(val, val, s[i][r]);
        }
      }
    }
    if constexpr (MODE == 3) {
      const int head = cb0 >> 6;  // wave's 64 cols = exactly one head
#pragma unroll
      for (int o = 1; o < 16; o <<= 1)
#pragma unroll
        for (int i = 0; i < 4; i++)
#pragma unroll
          for (int r = 0; r < 4; r++) s[i][r] += __shfl_xor(s[i][r], o);
      if (sub == 0) {
#pragma unroll
        for (int i = 0; i < 4; i++)
#pragma unroll
          for (int r = 0; r < 4; r++)
            Ks[(size_t)(rb0 + i * 16 + quad * 4 + r) * NH + head] = s[i][r];
      }
    }
  } else {
#pragma unroll
    for (int j = 0; j < 4; j++) {
      const int col = cb0 + j * 16 + sub;
      const float bv = bias[col];
#pragma unroll
      for (int i = 0; i < 4; i++) {
        const int row = rb0 + i * 16 + quad * 4;
#pragma unroll
        for (int r = 0; r < 4; r++) {
          const float val = acc[i][j][r] + bv;
          if constexpr (MODE == 0)
            ((float*)C0)[(size_t)(row + r) * N + col] = val;
          else
            ((__hip_bfloat16*)C0)[(size_t)(row + r) * N + col] = __float2bfloat16(val);
        }
      }
    }
  }
}

// ---------------------------------------------------------------------------
// feat_gemm: out[tok][h*64+f] = sum_dh in[tok][h*64+dh] * W0[h][dh][f]
// in given as bf16 hi+lo split; 3-term hi/lo MFMA for ~fp32 precision.
// grid: (NTOK/128, NH), block 256; wave handles 32 tokens.
// ---------------------------------------------------------------------------
__global__ __launch_bounds__(256) void feat_gemm_kernel(
    const short* __restrict__ xhi, const short* __restrict__ xlo,
    const short* __restrict__ Whi, const short* __restrict__ Wlo,
    float* __restrict__ outlog)
{
  const int lane = threadIdx.x & 63, wid = threadIdx.x >> 6;
  const int sub = lane & 15, quad = lane >> 4;
  const int h = blockIdx.y;
  const int tok0 = blockIdx.x * 128 + wid * 32;
  const short* Bh = Whi + (size_t)h * 4096;
  const short* Bl = Wlo + (size_t)h * 4096;

  f32x4_t acc[2][4] = {};
#pragma unroll
  for (int ks = 0; ks < 2; ks++) {
    const int ko = ks * 32 + quad * 8;
    bf16x8_t ah[2], al[2], bh[4], bl[4];
#pragma unroll
    for (int i = 0; i < 2; i++) {
      const size_t base = (size_t)(tok0 + i * 16 + sub) * DIMC + h * 64 + ko;
      ah[i] = *(const bf16x8_t*)(xhi + base);
      al[i] = *(const bf16x8_t*)(xlo + base);
    }
#pragma unroll
    for (int j = 0; j < 4; j++) {
      const size_t base = (size_t)(j * 16 + sub) * 64 + ko;
      bh[j] = *(const bf16x8_t*)(Bh + base);
      bl[j] = *(const bf16x8_t*)(Bl + base);
    }
#pragma unroll
    for (int i = 0; i < 2; i++)
#pragma unroll
      for (int j = 0; j < 4; j++) {
        acc[i][j] = __builtin_amdgcn_mfma_f32_16x16x32_bf16(ah[i], bh[j], acc[i][j], 0, 0, 0);
        acc[i][j] = __builtin_amdgcn_mfma_f32_16x16x32_bf16(al[i], bh[j], acc[i][j], 0, 0, 0);
        acc[i][j] = __builtin_amdgcn_mfma_f32_16x16x32_bf16(ah[i], bl[j], acc[i][j], 0, 0, 0);
      }
  }
#pragma unroll
  for (int i = 0; i < 2; i++)
#pragma unroll
    for (int j = 0; j < 4; j++)
#pragma unroll
      for (int r = 0; r < 4; r++)
        outlog[(size_t)(tok0 + i * 16 + quad * 4 + r) * DIMC + h * 64 + j * 16 + sub] = acc[i][j][r];
}

// ---------------------------------------------------------------------------
// Key summary: w[l,f] = exp(klog[l,h,f] - 0.5*ksq[l,h]); accumulate
//   partialN[f,d] += w[l,f]*v[l,d], partialD[f] += w[l,f].
// grid: (NCHK, NH, NB), block 256
// ---------------------------------------------------------------------------
__global__ __launch_bounds__(256) void kv_summary_kernel(
    const float* __restrict__ klog, const float* __restrict__ ksq,
    const __hip_bfloat16* __restrict__ vmat,
    float* __restrict__ pN, float* __restrict__ pD)
{
  const int chunk = blockIdx.x, h = blockIdx.y, b = blockIdx.z;
  const int lane = threadIdx.x & 63, wid = threadIdx.x >> 6;

  float Nacc[64];
#pragma unroll
  for (int f = 0; f < 64; f++) Nacc[f] = 0.f;
  float Dacc = 0.f;

  const int l0 = chunk * LCK;
  for (int li = wid; li < LCK; li += 4) {
    const int token = b * SL + l0 + li;
    const size_t base = (size_t)token * DIMC + h * DHC;
    const float kg = klog[base + lane];
    const float vl = __bfloat162float(vmat[base + lane]);
    const float w = __expf(kg - 0.5f * ksq[token * NH + h]);
    Dacc += w;
#pragma unroll
    for (int f = 0; f < 64; f++) Nacc[f] = fmaf(rlane(w, f), vl, Nacc[f]);
  }

  __shared__ float red[4096];
  for (int t = threadIdx.x; t < 4096; t += 256) red[t] = 0.f;
  __syncthreads();
  for (int r = 0; r < 4; r++) {
    if (wid == r) {
#pragma unroll
      for (int f = 0; f < 64; f++) red[f * 64 + lane] += Nacc[f];
    }
    __syncthreads();
  }
  const size_t pbase = ((size_t)((b * NH + h) * NCHK + chunk)) * 4096;
  for (int t = threadIdx.x; t < 4096; t += 256) pN[pbase + t] = red[t];

  __shared__ float dred[256];
  dred[threadIdx.x] = Dacc;
  __syncthreads();
  if (threadIdx.x < 64) {
    const float dsum = dred[threadIdx.x] + dred[64 + threadIdx.x] +
                       dred[128 + threadIdx.x] + dred[192 + threadIdx.x];
    pD[(size_t)((b * NH + h) * NCHK + chunk) * 64 + threadIdx.x] = dsum;
  }
}

// ---------------------------------------------------------------------------
// Combine chunk partials; write N^T (normalized, bf16 hi/lo, [d][f]) and
// normalized D (fp32). grid: (NB*NH, 16), block 256.
// ---------------------------------------------------------------------------
__global__ __launch_bounds__(256) void combine_nd_kernel(
    const float* __restrict__ pN, const float* __restrict__ pD,
    short* __restrict__ NfTh, short* __restrict__ NfTl, float* __restrict__ Df)
{
  const int bh = blockIdx.x, seg = blockIdx.y;
  __shared__ float sInv;
  float dsum = 0.f;
  if (threadIdx.x < 64) {
    for (int c = 0; c < NCHK; c++)
      dsum += pD[(size_t)(bh * NCHK + c) * 64 + threadIdx.x];
    float s = dsum;
#pragma unroll
    for (int o = 32; o; o >>= 1) s += __shfl_xor(s, o);
    if (threadIdx.x == 0) sInv = 1.f / s;
  }
  __syncthreads();
  const float inv = sInv;
  if (seg == 0 && threadIdx.x < 64) Df[bh * 64 + threadIdx.x] = dsum * inv;
  const int t = seg * 256 + threadIdx.x;   // t = f*64 + d
  float acc = 0.f;
  for (int c = 0; c < NCHK; c++)
    acc += pN[((size_t)(bh * NCHK + c)) * 4096 + t];
  const float val = acc * inv;
  const int f = t >> 6, d = t & 63;
  const __hip_bfloat16 hi = __float2bfloat16(val);
  const float rem = val - __bfloat162float(hi);
  const __hip_bfloat16 lo = __float2bfloat16(rem);
  NfTh[(size_t)bh * 4096 + d * 64 + f] = *(const short*)&hi;
  NfTl[(size_t)bh * 4096 + d * 64 + f] = *(const short*)&lo;
}

// ---------------------------------------------------------------------------
// phi: per (l,h): max-shifted exp of qlog, write e as bf16 hi/lo (A-layout
// [token][h*64+f]) and fused scale s = 1/(dt + eps*se).
// grid: (NCHQ, NH, NB), block 256
// ---------------------------------------------------------------------------
__global__ __launch_bounds__(256) void phi_kernel(
    const float* __restrict__ qlog, const float* __restrict__ Df,
    short* __restrict__ ehi, short* __restrict__ elo, float* __restrict__ sbuf)
{
  const int chunk = blockIdx.x, h = blockIdx.y, b = blockIdx.z;
  const int lane = threadIdx.x & 63, wid = threadIdx.x >> 6;
  const float Dl = Df[(b * NH + h) * 64 + lane];

  const int l0 = chunk * LCQ;
  for (int li = wid; li < LCQ; li += 4) {
    const int token = b * SL + l0 + li;
    const size_t base = (size_t)token * DIMC + h * DHC;
    const float lg = qlog[base + lane];

    float mx = lg;
#pragma unroll
    for (int o = 32; o; o >>= 1) mx = fmaxf(mx, __shfl_xor(mx, o));
    const float e = __expf(lg - mx);
    float se = e, dt = e * Dl;
#pragma unroll
    for (int o = 32; o; o >>= 1) { se += __shfl_xor(se, o); dt += __shfl_xor(dt, o); }

    const __hip_bfloat16 hi = __float2bfloat16(e);
    const float rem = e - __bfloat162float(hi);
    const __hip_bfloat16 lo = __float2bfloat16(rem);
    ehi[base + lane] = *(const short*)&hi;
    elo[base + lane] = *(const short*)&lo;
    if (lane == 0) sbuf[token * NH + h] = 1.f / (dt + FEPS * se);
  }
}

// ---------------------------------------------------------------------------
// ctx = (e @ N^T) * s : per (b,h) GEMM, M=tokens, N=64 d, K=64 f, 3-term hi/lo
// grid: (NTOK/128, NH), block 256; wave handles 32 tokens.
// ---------------------------------------------------------------------------
__global__ __launch_bounds__(256) void ctx_gemm_kernel(
    const short* __restrict__ ehi, const short* __restrict__ elo,
    const short* __restrict__ NfTh, const short* __restrict__ NfTl,
    const float* __restrict__ sbuf, __hip_bfloat16* __restrict__ ctx)
{
  const int lane = threadIdx.x & 63, wid = threadIdx.x >> 6;
  const int sub = lane & 15, quad = lane >> 4;
  const int h = blockIdx.y;
  const int tok0 = blockIdx.x * 128 + wid * 32;
  const int b = blockIdx.x >> 5;  // 32 x-blocks per batch (SL/128)
  const short* Bh = NfTh + ((size_t)(b * NH + h)) * 4096;
  const short* Bl = NfTl + ((size_t)(b * NH + h)) * 4096;

  f32x4_t acc[2][4] = {};
#pragma unroll
  for (int ks = 0; ks < 2; ks++) {
    const int ko = ks * 32 + quad * 8;
    bf16x8_t ah[2], al[2], bh[4], bl[4];
#pragma unroll
    for (int i = 0; i < 2; i++) {
      const size_t base = (size_t)(tok0 + i * 16 + sub) * DIMC + h * 64 + ko;
      ah[i] = *(const bf16x8_t*)(ehi + base);
      al[i] = *(const bf16x8_t*)(elo + base);
    }
#pragma unroll
    for (int j = 0; j < 4; j++) {
      const size_t base = (size_t)(j * 16 + sub) * 64 + ko;
      bh[j] = *(const bf16x8_t*)(Bh + base);
      bl[j] = *(const bf16x8_t*)(Bl + base);
    }
#pragma unroll
    for (int i = 0; i < 2; i++)
#pragma unroll
      for (int j = 0; j < 4; j++) {
        acc[i][j] = __builtin_amdgcn_mfma_f32_16x16x32_bf16(ah[i], bh[j], acc[i][j], 0, 0, 0);
        acc[i][j] = __builtin_amdgcn_mfma_f32_16x16x32_bf16(al[i], bh[j], acc[i][j], 0, 0, 0);
        acc[i][j] = __builtin_amdgcn_mfma_f32_16x16x32_bf16(ah[i], bl[j], acc[i][j], 0, 0, 0);
      }
  }
#pragma unroll
  for (int i = 0; i < 2; i++)
#pragma unroll
    for (int r = 0; r < 4; r++) {
      const int token = tok0 + i * 16 + quad * 4 + r;
      const float sv = sbuf[token * NH + h];
#pragma unroll
      for (int j = 0; j < 4; j++)
        ctx[(size_t)token * DIMC + h * 64 + j * 16 + sub] =
            __float2bfloat16(acc[i][j][r] * sv);
    }
}

// ---------------------------------------------------------------------------
extern "C" void kernel_launch(void* const* d_in, const int* in_sizes, int n_in,
                              void* d_out, int out_size, void* d_ws, size_t ws_size,
                              hipStream_t stream) {
  (void)in_sizes; (void)n_in; (void)out_size; (void)ws_size;
  const float* x   = (const float*)d_in[0];
  const float* Wq  = (const float*)d_in[1];
  const float* bq  = (const float*)d_in[2];
  const float* Wk  = (const float*)d_in[3];
  const float* bk  = (const float*)d_in[4];
  const float* Wv  = (const float*)d_in[5];
  const float* bv  = (const float*)d_in[6];
  const float* Wo  = (const float*)d_in[7];
  const float* bo  = (const float*)d_in[8];
  const float* Wrf = (const float*)d_in[9];
  float* out = (float*)d_out;

  constexpr size_t MiB = 1u << 20;
  constexpr size_t KiB = 1u << 10;
  constexpr size_t NTOK = (size_t)NB * SL;   // 16384
  constexpr size_t XN   = NTOK * DIMC;
  constexpr size_t WN   = (size_t)DIMC * DIMC;

  char* ws = (char*)d_ws;
  short* xb   = (short*)(ws);                        // bf16 x, 32 MiB; later ctxb
  short* Wkb  = (short*)(ws + 32 * MiB);
  short* Wvb  = (short*)(ws + 34 * MiB);
  short* Wob  = (short*)(ws + 36 * MiB);
  short* Wqb  = (short*)(ws + 38 * MiB);
  short* W0Th = (short*)(ws + 40 * MiB);             // 128 KiB
  short* W0Tl = (short*)(ws + 40 * MiB + 128 * KiB); // 128 KiB
  float* ksq  = (float*)(ws + 41 * MiB);             // 1 MiB
  float* sbuf = (float*)(ws + 42 * MiB);             // 1 MiB
  float* pD   = (float*)(ws + 43 * MiB);             // 512 KiB
  short* NfTh = (short*)(ws + 43 * MiB + 512 * KiB); // 512 KiB
  short* NfTl = (short*)(ws + 44 * MiB);             // 512 KiB
  float* Df   = (float*)(ws + 44 * MiB + 512 * KiB); // 16 KiB
  float* klog = (float*)(ws + 45 * MiB);             // 64 MiB [45..109)
  __hip_bfloat16* khi = (__hip_bfloat16*)(ws + 109 * MiB);  // 32 MiB
  __hip_bfloat16* klo = (__hip_bfloat16*)(ws + 141 * MiB);  // 32 MiB
  __hip_bfloat16* vb  = (__hip_bfloat16*)(ws + 173 * MiB);  // 32 MiB
  // overlays (all precede their overwrite in stream order):
  float* pN   = (float*)(ws + 109 * MiB);            // 32 MiB over khi (dead after feat_gemm k)
  __hip_bfloat16* qhi = (__hip_bfloat16*)(ws + 45 * MiB);   // over klog (dead after kv_summary)
  __hip_bfloat16* qlo = (__hip_bfloat16*)(ws + 77 * MiB);
  float* qlog = (float*)(ws + 141 * MiB);            // 64 MiB over klo+vb (dead)
  short* ehi  = (short*)(ws + 45 * MiB);             // over qhi/qlo (dead after feat_gemm q)
  short* elo  = (short*)(ws + 77 * MiB);
  __hip_bfloat16* ctxb = (__hip_bfloat16*)xb;        // over xb (dead after q GEMM)

  const dim3 blk(256);

  cast_f32_to_bf16<<<dim3(XN / 1024), blk, 0, stream>>>(x, xb, (int)XN);
  cast_f32_to_bf16<<<dim3(WN / 1024), blk, 0, stream>>>(Wk, Wkb, (int)WN);
  cast_f32_to_bf16<<<dim3(WN / 1024), blk, 0, stream>>>(Wv, Wvb, (int)WN);
  cast_f32_to_bf16<<<dim3(WN / 1024), blk, 0, stream>>>(Wo, Wob, (int)WN);
  cast_f32_to_bf16<<<dim3(WN / 1024), blk, 0, stream>>>(Wq, Wqb, (int)WN);
  prep_w0t_kernel<<<dim3(NH), blk, 0, stream>>>(Wrf, W0Th, W0Tl);

  const dim3 gg(NTOK / 128, DIMC / 128);
  gemm_lds_kernel<3><<<gg, blk, 0, stream>>>(xb, Wkb, bk, khi, klo, ksq);
  gemm_lds_kernel<1><<<gg, blk, 0, stream>>>(xb, Wvb, bv, vb, nullptr, nullptr);

  feat_gemm_kernel<<<dim3(NTOK / 128, NH), blk, 0, stream>>>(
      (const short*)khi, (const short*)klo, W0Th, W0Tl, klog);

  kv_summary_kernel<<<dim3(NCHK, NH, NB), blk, 0, stream>>>(klog, ksq, vb, pN, pD);
  combine_nd_kernel<<<dim3(NB * NH, 16), blk, 0, stream>>>(pN, pD, NfTh, NfTl, Df);

  gemm_lds_kernel<4><<<gg, blk, 0, stream>>>(xb, Wqb, bq, qhi, qlo, nullptr);
  feat_gemm_kernel<<<dim3(NTOK / 128, NH), blk, 0, stream>>>(
      (const short*)qhi, (const short*)qlo, W0Th, W0Tl, qlog);
  phi_kernel<<<dim3(NCHQ, NH, NB), blk, 0, stream>>>(qlog, Df, ehi, elo, sbuf);
  ctx_gemm_kernel<<<dim3(NTOK / 128, NH), blk, 0, stream>>>(
      ehi, elo, NfTh, NfTl, sbuf, ctxb);

  gemm_lds_kernel<0><<<gg, blk, 0, stream>>>((const short*)ctxb, Wob, bo, out, nullptr, nullptr);
}